// Round 5
// baseline (743.245 us; speedup 1.0000x reference)
//
#include <hip/hip_runtime.h>
#include <stdint.h>

typedef __bf16 bf16;
typedef bf16 bf16x8 __attribute__((ext_vector_type(8)));
typedef float f32x4 __attribute__((ext_vector_type(4)));
typedef float f32x16 __attribute__((ext_vector_type(16)));

#define EMBED 512
#define NHEAD 8
#define DEPTH 64
#define BATCH 2
#define SEQ 4096
#define M_TOTAL (BATCH * SEQ)

#define LOG2E 1.44269504f
#define QSCALE (0.125f * LOG2E)  // folded into q projection (log2 domain)
#define MASKC (-1.0e9f * LOG2E)
#define DEFER_THR 10.0f

// ---------------- helpers ----------------
__device__ __forceinline__ void gload16(const void* g, void* l) {
  __builtin_amdgcn_global_load_lds((const __attribute__((address_space(1))) unsigned*)g,
                                   (__attribute__((address_space(3))) unsigned*)l, 16, 0, 0);
}
__device__ __forceinline__ uint32_t cvtpk(float a, float b) {
  uint32_t r;
  asm volatile("v_cvt_pk_bf16_f32 %0, %1, %2" : "=v"(r) : "v"(a), "v"(b));
  return r;
}
__device__ __forceinline__ void plswap(uint32_t& a, uint32_t& b) {
  asm volatile("v_permlane32_swap_b32 %0, %1" : "+v"(a), "+v"(b));
}
__device__ __forceinline__ float vdup(float x) {
  float r;
  asm volatile("v_mov_b32 %0, %1" : "=v"(r) : "v"(x));
  return r;
}
__device__ __forceinline__ float cross_max(float x) {
  float a = x, b = vdup(x);
  asm volatile("v_permlane32_swap_b32 %0, %1" : "+v"(a), "+v"(b));
  return fmaxf(a, b);
}
__device__ __forceinline__ float cross_sum(float x) {
  float a = x, b = vdup(x);
  asm volatile("v_permlane32_swap_b32 %0, %1" : "+v"(a), "+v"(b));
  return a + b;
}
__device__ __forceinline__ float max3f(float a, float b, float c) {
  return fmaxf(fmaxf(a, b), c);
}
union U4 { uint32_t u[4]; bf16x8 v; };

// ---------------- prep: fp32->bf16 of q,k,v + 4 weight transposes, one dispatch ----
__global__ __launch_bounds__(256) void prep(const float* __restrict__ q, const float* __restrict__ k,
                                            const float* __restrict__ v, bf16* __restrict__ oq,
                                            bf16* __restrict__ ok, bf16* __restrict__ ov,
                                            const float* __restrict__ W0, const float* __restrict__ W1,
                                            const float* __restrict__ W2, const float* __restrict__ W3,
                                            bf16* __restrict__ T0, bf16* __restrict__ T1,
                                            bf16* __restrict__ T2, bf16* __restrict__ T3) {
  __shared__ float t[32][33];
  int z = blockIdx.y;
  if (z < 3) {
    const float* in = z == 0 ? q : (z == 1 ? k : v);
    bf16* out = z == 0 ? oq : (z == 1 ? ok : ov);
    size_t i = ((size_t)blockIdx.x * 256 + threadIdx.x) * 8;
    float4 f0 = *(const float4*)(in + i);
    float4 f1 = *(const float4*)(in + i + 4);
    bf16x8 o;
    o[0] = (bf16)f0.x; o[1] = (bf16)f0.y; o[2] = (bf16)f0.z; o[3] = (bf16)f0.w;
    o[4] = (bf16)f1.x; o[5] = (bf16)f1.y; o[6] = (bf16)f1.z; o[7] = (bf16)f1.w;
    *(bf16x8*)(out + i) = o;
  } else {
    int bx = blockIdx.x;
    if (bx >= 1024) return;
    int wsel = bx >> 8, rem = bx & 255;
    const float* W = wsel == 0 ? W0 : (wsel == 1 ? W1 : (wsel == 2 ? W2 : W3));
    bf16* WT = wsel == 0 ? T0 : (wsel == 1 ? T1 : (wsel == 2 ? T2 : T3));
    int k0 = (rem >> 4) * 32, n0 = (rem & 15) * 32;
    int x = threadIdx.x & 31, y = threadIdx.x >> 5;
#pragma unroll
    for (int yy = y; yy < 32; yy += 8)
      t[yy][x] = W[(size_t)(k0 + yy) * EMBED + n0 + x];
    __syncthreads();
#pragma unroll
    for (int yy = y; yy < 32; yy += 8)
      WT[(size_t)(n0 + yy) * EMBED + k0 + x] = (bf16)t[x][yy];
  }
}

// ---------------- 128x128 GEMM body (XCD-swizzled block ids) ----------------
__device__ __forceinline__ void gemm128_body(const bf16* __restrict__ A, const bf16* __restrict__ Bt,
                                             const float* __restrict__ bias, void* __restrict__ out,
                                             float scale, int mode) {
  __shared__ __align__(16) bf16 As[128 * 64];
  __shared__ __align__(16) bf16 Bs[128 * 64];
  int tid = threadIdx.x, lane = tid & 63, w = tid >> 6;
  int g = lane >> 4, r = lane & 15;
  // XCD swizzle: 256 blocks/slice, 32-chunk per XCD keeps same-A-panel blocks together
  int orig = blockIdx.y * gridDim.x + blockIdx.x;
  int wid = (orig & 7) * 32 + (orig >> 3);
  int n0 = (wid & 3) * 128, m0 = (wid >> 2) * 128;
  int wr = (w >> 1) * 64, wc = (w & 1) * 64;

  f32x4 acc[4][4];
#pragma unroll
  for (int m = 0; m < 4; m++)
#pragma unroll
    for (int n = 0; n < 4; n++)
#pragma unroll
      for (int i = 0; i < 4; i++) acc[m][n][i] = 0.f;

  size_t aoff[4], boff[4];
#pragma unroll
  for (int i = 0; i < 4; i++) {
    int u = w * 64 + lane + i * 256;
    int row = u >> 3, scs = (u & 7) ^ (row & 7);
    aoff[i] = (size_t)(m0 + row) * EMBED + scs * 8;
    boff[i] = (size_t)(n0 + row) * EMBED + scs * 8;
  }

  for (int k0 = 0; k0 < EMBED; k0 += 64) {
#pragma unroll
    for (int i = 0; i < 4; i++) {
      gload16(A + aoff[i] + k0, &As[(w + i * 4) * 512]);
      gload16(Bt + boff[i] + k0, &Bs[(w + i * 4) * 512]);
    }
    __syncthreads();
#pragma unroll
    for (int kk = 0; kk < 64; kk += 32) {
      bf16x8 af[4], bf_[4];
#pragma unroll
      for (int m = 0; m < 4; m++) {
        int row = wr + m * 16 + r;
        af[m] = *(const bf16x8*)&As[row * 64 + (((kk >> 3) + g) ^ (r & 7)) * 8];
      }
#pragma unroll
      for (int n = 0; n < 4; n++) {
        int col = wc + n * 16 + r;
        bf_[n] = *(const bf16x8*)&Bs[col * 64 + (((kk >> 3) + g) ^ (r & 7)) * 8];
      }
      __builtin_amdgcn_s_setprio(1);
#pragma unroll
      for (int m = 0; m < 4; m++)
#pragma unroll
        for (int n = 0; n < 4; n++)
          acc[m][n] = __builtin_amdgcn_mfma_f32_16x16x32_bf16(af[m], bf_[n], acc[m][n], 0, 0, 0);
      __builtin_amdgcn_s_setprio(0);
    }
    __syncthreads();
  }

#pragma unroll
  for (int n = 0; n < 4; n++) {
    int ncol = n0 + wc + n * 16 + r;
    float bv = bias[ncol];
#pragma unroll
    for (int m = 0; m < 4; m++)
#pragma unroll
      for (int v_ = 0; v_ < 4; v_++) {
        int mrow = m0 + wr + m * 16 + g * 4 + v_;
        float val = (acc[m][n][v_] + bv) * scale;
        if (mode == 2) {
          ((float*)out)[(size_t)mrow * EMBED + ncol] = val;
        } else {
          int b = mrow >> 12, s = mrow & (SEQ - 1);
          int h = ncol >> 6, d = ncol & 63;
          size_t idx = (mode == 0) ? ((((size_t)(b * NHEAD + h)) * SEQ + s) * DEPTH + d)
                                   : ((((size_t)(b * NHEAD + h)) * DEPTH + d) * SEQ + s);
          ((bf16*)out)[idx] = (bf16)val;
        }
      }
  }
}

__global__ __launch_bounds__(256, 2) void gemm_qkv(const bf16* __restrict__ Xq, const bf16* __restrict__ Xk,
                                                   const bf16* __restrict__ Xv, const bf16* __restrict__ Tq,
                                                   const bf16* __restrict__ Tk, const bf16* __restrict__ Tv,
                                                   const float* __restrict__ bq, const float* __restrict__ bk,
                                                   const float* __restrict__ bv, bf16* __restrict__ qh,
                                                   bf16* __restrict__ kh, bf16* __restrict__ vT) {
  int z = blockIdx.z;
  const bf16* A = z == 0 ? Xq : (z == 1 ? Xk : Xv);
  const bf16* Bt = z == 0 ? Tq : (z == 1 ? Tk : Tv);
  const float* bias = z == 0 ? bq : (z == 1 ? bk : bv);
  void* out = z == 0 ? (void*)qh : (z == 1 ? (void*)kh : (void*)vT);
  float scale = z == 0 ? QSCALE : 1.0f;
  int mode = z == 2 ? 1 : 0;
  gemm128_body(A, Bt, bias, out, scale, mode);
}

__global__ __launch_bounds__(256, 2) void gemm_o(const bf16* __restrict__ A, const bf16* __restrict__ Bt,
                                                 const float* __restrict__ bias, float* __restrict__ out) {
  gemm128_body(A, Bt, bias, out, 1.0f, 2);
}

// ---------------- flash attention: 4-wave blocks, 64 q/wave, full KV ----------------
// grid 256 blocks, 256 thr. LDS 32KB -> 4 blocks/CU (16 waves in 4 independent groups).
// LDS layout (bytes): K(buf) = buf*8192, V(buf) = 16384 + buf*8192; row=128B, XOR-swz.
// KV loop unrolled x2 so buf is compile-time -> all ds_reads = 4 vaddrs + imm offsets.
template <int BUF>
__device__ __forceinline__ void tile_step(const char* rb, const int (&va)[4],
                                          const bf16* kg0, const bf16* vg0, char* kvb,
                                          const float* maskb, int kv, bool stage_next,
                                          const bf16x8 (&qf)[2][4], f32x16 (&oacc)[2][2],
                                          float (&mrun)[2], float (&lrun)[2], int hi) {
  if (stage_next) {
    int nkv = kv + 64;
    gload16(kg0 + (size_t)nkv * DEPTH, kvb + (BUF ^ 1) * 8192);
    gload16(kg0 + (size_t)(nkv + 32) * DEPTH, kvb + (BUF ^ 1) * 8192 + 4096);
    gload16(vg0 + nkv, kvb + 16384 + (BUF ^ 1) * 8192);
    gload16(vg0 + 32 * SEQ + nkv, kvb + 16384 + (BUF ^ 1) * 8192 + 4096);
  }
  // mask prescale -> sacc init (replaces zero-init + post-MFMA fma)
  f32x16 minit[2];
#pragma unroll
  for (int m2 = 0; m2 < 2; m2++)
#pragma unroll
    for (int g = 0; g < 4; g++) {
      f32x4 f = *(const f32x4*)(maskb + kv + m2 * 32 + g * 8 + 4 * hi);
#pragma unroll
      for (int i = 0; i < 4; i++) minit[m2][4 * g + i] = f[i] * MASKC;
    }
  // K frags (shared by both q2)
  bf16x8 kf[2][4];
#pragma unroll
  for (int m2 = 0; m2 < 2; m2++)
#pragma unroll
    for (int s = 0; s < 4; s++)
      kf[m2][s] = *(const bf16x8*)(rb + va[s] + BUF * 8192 + m2 * 4096);

  bf16x8 pa[2][4];
#pragma unroll
  for (int q2 = 0; q2 < 2; q2++) {
    f32x16 s0 = minit[0], s1 = minit[1];
    __builtin_amdgcn_s_setprio(1);
#pragma unroll
    for (int s = 0; s < 4; s++) {
      s0 = __builtin_amdgcn_mfma_f32_32x32x16_bf16(kf[0][s], qf[q2][s], s0, 0, 0, 0);
      s1 = __builtin_amdgcn_mfma_f32_32x32x16_bf16(kf[1][s], qf[q2][s], s1, 0, 0, 0);
    }
    __builtin_amdgcn_s_setprio(0);

    // row max: v_max3 tree + cross-half permlane
    float mx[16];
#pragma unroll
    for (int i = 0; i < 16; i++) mx[i] = fmaxf(s0[i], s1[i]);
    float u0 = max3f(mx[0], mx[1], mx[2]);
    float u1 = max3f(mx[3], mx[4], mx[5]);
    float u2 = max3f(mx[6], mx[7], mx[8]);
    float u3 = max3f(mx[9], mx[10], mx[11]);
    float u4 = max3f(mx[12], mx[13], mx[14]);
    float pmax = fmaxf(max3f(u0, u1, u2), max3f(u3, u4, mx[15]));
    pmax = cross_max(pmax);

    // defer-max (T13)
    if (__any(pmax > mrun[q2] + DEFER_THR)) {
      float mnew = fmaxf(mrun[q2], pmax);
      float alpha = exp2f(mrun[q2] - mnew);
      lrun[q2] *= alpha;
      mrun[q2] = mnew;
#pragma unroll
      for (int r = 0; r < 16; r++) {
        float af = __shfl(alpha, (r & 3) + 8 * (r >> 2) + 4 * hi);
        oacc[q2][0][r] *= af;
        oacc[q2][1][r] *= af;
      }
    }

    // P = exp2(S - m), row sum
    float p[32];
    float rsv[4] = {0.f, 0.f, 0.f, 0.f};
#pragma unroll
    for (int i = 0; i < 16; i++) {
      p[i] = __builtin_amdgcn_exp2f(s0[i] - mrun[q2]);
      rsv[i & 3] += p[i];
    }
#pragma unroll
    for (int i = 0; i < 16; i++) {
      p[16 + i] = __builtin_amdgcn_exp2f(s1[i] - mrun[q2]);
      rsv[i & 3] += p[16 + i];
    }
    lrun[q2] += cross_sum((rsv[0] + rsv[1]) + (rsv[2] + rsv[3]));

    // P -> A-frags (T12)
#pragma unroll
    for (int m2 = 0; m2 < 2; m2++) {
      uint32_t c0 = cvtpk(p[m2 * 16 + 0], p[m2 * 16 + 1]);
      uint32_t c1 = cvtpk(p[m2 * 16 + 2], p[m2 * 16 + 3]);
      uint32_t d0 = cvtpk(p[m2 * 16 + 4], p[m2 * 16 + 5]);
      uint32_t d1 = cvtpk(p[m2 * 16 + 6], p[m2 * 16 + 7]);
      plswap(c0, d0);
      plswap(c1, d1);
      U4 e; e.u[0] = c0; e.u[1] = c1; e.u[2] = d0; e.u[3] = d1;
      pa[q2][m2 * 2 + 0] = e.v;
      uint32_t c2 = cvtpk(p[m2 * 16 + 8], p[m2 * 16 + 9]);
      uint32_t c3 = cvtpk(p[m2 * 16 + 10], p[m2 * 16 + 11]);
      uint32_t d2 = cvtpk(p[m2 * 16 + 12], p[m2 * 16 + 13]);
      uint32_t d3 = cvtpk(p[m2 * 16 + 14], p[m2 * 16 + 15]);
      plswap(c2, d2);
      plswap(c3, d3);
      U4 o; o.u[0] = c2; o.u[1] = c3; o.u[2] = d2; o.u[3] = d3;
      pa[q2][m2 * 2 + 1] = o.v;
    }
  }

  // O += P V
  __builtin_amdgcn_s_setprio(1);
#pragma unroll
  for (int nb = 0; nb < 2; nb++)
#pragma unroll
    for (int ks = 0; ks < 4; ks++) {
      bf16x8 vf = *(const bf16x8*)(rb + va[ks] + 16384 + BUF * 8192 + nb * 4096);
      oacc[0][nb] = __builtin_amdgcn_mfma_f32_32x32x16_bf16(pa[0][ks], vf, oacc[0][nb], 0, 0, 0);
      oacc[1][nb] = __builtin_amdgcn_mfma_f32_32x32x16_bf16(pa[1][ks], vf, oacc[1][nb], 0, 0, 0);
    }
  __builtin_amdgcn_s_setprio(0);
  __syncthreads();
}

__global__ __launch_bounds__(256, 4) void flash_attn(const bf16* __restrict__ qh,
                                                     const bf16* __restrict__ kh,
                                                     const bf16* __restrict__ vT,
                                                     const float* __restrict__ mask,
                                                     bf16* __restrict__ O) {
  __shared__ __align__(16) unsigned char smem[32768];
  int tid = threadIdx.x, lane = tid & 63, w = tid >> 6;
  int l31 = lane & 31, hi = lane >> 5, l7 = lane & 7;
  // XCD swizzle: 256 blocks; chunk of 32 keeps 2 full bh per XCD (K/V L2-resident)
  int orig = blockIdx.y * 16 + blockIdx.x;
  int wid = (orig & 7) * 32 + (orig >> 3);
  int qblk = wid & 15, bh = wid >> 4;
  int b = bh >> 3, h = bh & 7;
  int q0 = qblk * 256;
  const bf16* Qb = qh + (size_t)bh * SEQ * DEPTH;
  const bf16* Kb = kh + (size_t)bh * SEQ * DEPTH;
  const bf16* Vb = vT + (size_t)bh * DEPTH * SEQ;
  const float* maskb = mask + (size_t)b * SEQ;

  // staging source (pre-swizzled col, rule 21); dest wave-uniform base
  int srow = tid >> 3;
  int scs = (tid & 7) ^ (srow & 7);
  const bf16* kg0 = Kb + (size_t)srow * DEPTH + scs * 8;
  const bf16* vg0 = Vb + (size_t)srow * SEQ + scs * 8;
  char* kvb = (char*)smem + w * 1024;
  const char* rb = (const char*)smem;

  // loop-invariant read vaddrs (shared K/V via imm offsets)
  int va[4];
#pragma unroll
  for (int s = 0; s < 4; s++) va[s] = l31 * 128 + (((s * 2 + hi) ^ l7) * 16);

  // prologue: stage tile 0
  gload16(kg0, kvb);
  gload16(kg0 + (size_t)32 * DEPTH, kvb + 4096);
  gload16(vg0, kvb + 16384);
  gload16(vg0 + 32 * SEQ, kvb + 16384 + 4096);

  // Q fragments (64 q-rows/wave), resident whole kernel
  bf16x8 qf[2][4];
#pragma unroll
  for (int q2 = 0; q2 < 2; q2++) {
    const bf16* qp = Qb + (size_t)(q0 + w * 64 + q2 * 32 + l31) * DEPTH + hi * 8;
#pragma unroll
    for (int s = 0; s < 4; s++) qf[q2][s] = *(const bf16x8*)(qp + s * 16);
  }

  f32x16 oacc[2][2];
#pragma unroll
  for (int q2 = 0; q2 < 2; q2++)
#pragma unroll
    for (int nb = 0; nb < 2; nb++)
#pragma unroll
      for (int i = 0; i < 16; i++) oacc[q2][nb][i] = 0.f;
  float mrun[2] = {-__builtin_inff(), -__builtin_inff()};
  float lrun[2] = {0.f, 0.f};

  __syncthreads();

#pragma unroll 1
  for (int kv = 0; kv < SEQ; kv += 128) {
    tile_step<0>(rb, va, kg0, vg0, kvb, maskb, kv, true, qf, oacc, mrun, lrun, hi);
    tile_step<1>(rb, va, kg0, vg0, kvb, maskb, kv + 64, kv + 128 < SEQ, qf, oacc, mrun, lrun, hi);
  }

  // epilogue: O /= l, write [B][S][E] bf16
  float invl[2] = {1.0f / lrun[0], 1.0f / lrun[1]};
  bf16* Ob = O + ((size_t)(b * SEQ + q0 + w * 64)) * EMBED + h * DEPTH + l31;
#pragma unroll
  for (int q2 = 0; q2 < 2; q2++)
#pragma unroll
    for (int nb = 0; nb < 2; nb++)
#pragma unroll
      for (int r = 0; r < 16; r++) {
        int cr = (r & 3) + 8 * (r >> 2) + 4 * hi;
        float iv = __shfl(invl[q2], cr);
        Ob[(size_t)(q2 * 32 + cr) * EMBED + nb * 32] = (bf16)(oacc[q2][nb][r] * iv);
      }
}

// ---------------- launch ----------------
extern "C" void kernel_launch(void* const* d_in, const int* in_sizes, int n_in,
                              void* d_out, int out_size, void* d_ws, size_t ws_size,
                              hipStream_t stream) {
  (void)in_sizes; (void)n_in; (void)out_size; (void)ws_size;
  const float* q = (const float*)d_in[0];
  const float* k = (const float*)d_in[1];
  const float* v = (const float*)d_in[2];
  const float* mask = (const float*)d_in[3];
  const float* Wq = (const float*)d_in[4];
  const float* bq = (const float*)d_in[5];
  const float* Wk = (const float*)d_in[6];
  const float* bk = (const float*)d_in[7];
  const float* Wv = (const float*)d_in[8];
  const float* bv = (const float*)d_in[9];
  const float* Wo = (const float*)d_in[10];
  const float* bo = (const float*)d_in[11];

  const size_t NX = (size_t)M_TOTAL * EMBED;
  const size_t NW = (size_t)EMBED * EMBED;
  bf16* Xq = (bf16*)d_ws;
  bf16* Xk = Xq + NX;
  bf16* Xv = Xk + NX;
  bf16* WTq = Xv + NX;
  bf16* WTk = WTq + NW;
  bf16* WTv = WTk + NW;
  bf16* WTo = WTv + NW;
  bf16* qh = WTo + NW;
  bf16* kh = qh + NX;
  bf16* vT = kh + NX;
  bf16* Ow = vT + NX;

  prep<<<dim3(NX / 2048, 4), 256, 0, stream>>>(q, k, v, Xq, Xk, Xv, Wq, Wk, Wv, Wo,
                                               WTq, WTk, WTv, WTo);

  gemm_qkv<<<dim3(EMBED / 128, M_TOTAL / 128, 3), 256, 0, stream>>>(
      Xq, Xk, Xv, WTq, WTk, WTv, bq, bk, bv, qh, kh, vT);

  flash_attn<<<dim3(16, 16), 256, 0, stream>>>(qh, kh, vT, mask, Ow);

  gemm_o<<<dim3(EMBED / 128, M_TOTAL / 128), 256, 0, stream>>>(Ow, WTo, bo, (float*)d_out);
}

// Round 7
// 262.296 us; speedup vs baseline: 2.8336x; 2.8336x over previous
//
#include <hip/hip_runtime.h>
#include <stdint.h>

typedef __bf16 bf16;
typedef bf16 bf16x8 __attribute__((ext_vector_type(8)));
typedef float f32x4 __attribute__((ext_vector_type(4)));
typedef float f32x16 __attribute__((ext_vector_type(16)));

#define EMBED 512
#define NHEAD 8
#define DEPTH 64
#define BATCH 2
#define SEQ 4096
#define M_TOTAL (BATCH * SEQ)
#define KVH 2048  // keys per wave-half (split-KV)

#define LOG2E 1.44269504f
#define QSCALE (0.125f * LOG2E)  // folded into q projection (log2 domain)
#define MASKC (-1.0e9f * LOG2E)
#define DEFER_THR 10.0f

// ---------------- helpers ----------------
__device__ __forceinline__ void gload16(const void* g, void* l) {
  __builtin_amdgcn_global_load_lds((const __attribute__((address_space(1))) unsigned*)g,
                                   (__attribute__((address_space(3))) unsigned*)l, 16, 0, 0);
}
__device__ __forceinline__ uint32_t cvtpk(float a, float b) {
  uint32_t r;
  asm volatile("v_cvt_pk_bf16_f32 %0, %1, %2" : "=v"(r) : "v"(a), "v"(b));
  return r;
}
__device__ __forceinline__ void plswap(uint32_t& a, uint32_t& b) {
  asm volatile("v_permlane32_swap_b32 %0, %1" : "+v"(a), "+v"(b));
}
__device__ __forceinline__ float vdup(float x) {
  float r;
  asm volatile("v_mov_b32 %0, %1" : "=v"(r) : "v"(x));
  return r;
}
__device__ __forceinline__ float cross_max(float x) {
  float a = x, b = vdup(x);
  asm volatile("v_permlane32_swap_b32 %0, %1" : "+v"(a), "+v"(b));
  return fmaxf(a, b);
}
__device__ __forceinline__ float cross_sum(float x) {
  float a = x, b = vdup(x);
  asm volatile("v_permlane32_swap_b32 %0, %1" : "+v"(a), "+v"(b));
  return a + b;
}
__device__ __forceinline__ float max3f(float a, float b, float c) {
  return fmaxf(fmaxf(a, b), c);
}
union U4 { uint32_t u[4]; bf16x8 v; };

// ---------------- prep: fp32->bf16 of q,k,v + 4 weight transposes ----------------
__global__ __launch_bounds__(256) void prep(const float* __restrict__ q, const float* __restrict__ k,
                                            const float* __restrict__ v, bf16* __restrict__ oq,
                                            bf16* __restrict__ ok, bf16* __restrict__ ov,
                                            const float* __restrict__ W0, const float* __restrict__ W1,
                                            const float* __restrict__ W2, const float* __restrict__ W3,
                                            bf16* __restrict__ T0, bf16* __restrict__ T1,
                                            bf16* __restrict__ T2, bf16* __restrict__ T3) {
  __shared__ float t[32][33];
  int z = blockIdx.y;
  if (z < 3) {
    const float* in = z == 0 ? q : (z == 1 ? k : v);
    bf16* out = z == 0 ? oq : (z == 1 ? ok : ov);
    size_t i = ((size_t)blockIdx.x * 256 + threadIdx.x) * 8;
    float4 f0 = *(const float4*)(in + i);
    float4 f1 = *(const float4*)(in + i + 4);
    bf16x8 o;
    o[0] = (bf16)f0.x; o[1] = (bf16)f0.y; o[2] = (bf16)f0.z; o[3] = (bf16)f0.w;
    o[4] = (bf16)f1.x; o[5] = (bf16)f1.y; o[6] = (bf16)f1.z; o[7] = (bf16)f1.w;
    *(bf16x8*)(out + i) = o;
  } else {
    int bx = blockIdx.x;
    if (bx >= 1024) return;
    int wsel = bx >> 8, rem = bx & 255;
    const float* W = wsel == 0 ? W0 : (wsel == 1 ? W1 : (wsel == 2 ? W2 : W3));
    bf16* WT = wsel == 0 ? T0 : (wsel == 1 ? T1 : (wsel == 2 ? T2 : T3));
    int k0 = (rem >> 4) * 32, n0 = (rem & 15) * 32;
    int x = threadIdx.x & 31, y = threadIdx.x >> 5;
#pragma unroll
    for (int yy = y; yy < 32; yy += 8)
      t[yy][x] = W[(size_t)(k0 + yy) * EMBED + n0 + x];
    __syncthreads();
#pragma unroll
    for (int yy = y; yy < 32; yy += 8)
      WT[(size_t)(n0 + yy) * EMBED + k0 + x] = (bf16)t[x][yy];
  }
}

// ---------------- 128x128 GEMM body (XCD-swizzled block ids) ----------------
__device__ __forceinline__ void gemm128_body(const bf16* __restrict__ A, const bf16* __restrict__ Bt,
                                             const float* __restrict__ bias, void* __restrict__ out,
                                             float scale, int mode) {
  __shared__ __align__(16) bf16 As[128 * 64];
  __shared__ __align__(16) bf16 Bs[128 * 64];
  int tid = threadIdx.x, lane = tid & 63, w = tid >> 6;
  int g = lane >> 4, r = lane & 15;
  int orig = blockIdx.y * gridDim.x + blockIdx.x;
  int wid = (orig & 7) * 32 + (orig >> 3);  // 256 blocks: bijective XCD chunking
  int n0 = (wid & 3) * 128, m0 = (wid >> 2) * 128;
  int wr = (w >> 1) * 64, wc = (w & 1) * 64;

  f32x4 acc[4][4];
#pragma unroll
  for (int m = 0; m < 4; m++)
#pragma unroll
    for (int n = 0; n < 4; n++)
#pragma unroll
      for (int i = 0; i < 4; i++) acc[m][n][i] = 0.f;

  size_t aoff[4], boff[4];
#pragma unroll
  for (int i = 0; i < 4; i++) {
    int u = w * 64 + lane + i * 256;
    int row = u >> 3, scs = (u & 7) ^ (row & 7);
    aoff[i] = (size_t)(m0 + row) * EMBED + scs * 8;
    boff[i] = (size_t)(n0 + row) * EMBED + scs * 8;
  }

  for (int k0 = 0; k0 < EMBED; k0 += 64) {
#pragma unroll
    for (int i = 0; i < 4; i++) {
      gload16(A + aoff[i] + k0, &As[(w + i * 4) * 512]);
      gload16(Bt + boff[i] + k0, &Bs[(w + i * 4) * 512]);
    }
    __syncthreads();
#pragma unroll
    for (int kk = 0; kk < 64; kk += 32) {
      bf16x8 af[4], bf_[4];
#pragma unroll
      for (int m = 0; m < 4; m++) {
        int row = wr + m * 16 + r;
        af[m] = *(const bf16x8*)&As[row * 64 + (((kk >> 3) + g) ^ (r & 7)) * 8];
      }
#pragma unroll
      for (int n = 0; n < 4; n++) {
        int col = wc + n * 16 + r;
        bf_[n] = *(const bf16x8*)&Bs[col * 64 + (((kk >> 3) + g) ^ (r & 7)) * 8];
      }
      __builtin_amdgcn_s_setprio(1);
#pragma unroll
      for (int m = 0; m < 4; m++)
#pragma unroll
        for (int n = 0; n < 4; n++)
          acc[m][n] = __builtin_amdgcn_mfma_f32_16x16x32_bf16(af[m], bf_[n], acc[m][n], 0, 0, 0);
      __builtin_amdgcn_s_setprio(0);
    }
    __syncthreads();
  }

#pragma unroll
  for (int n = 0; n < 4; n++) {
    int ncol = n0 + wc + n * 16 + r;
    float bv = bias[ncol];
#pragma unroll
    for (int m = 0; m < 4; m++)
#pragma unroll
      for (int v_ = 0; v_ < 4; v_++) {
        int mrow = m0 + wr + m * 16 + g * 4 + v_;
        float val = (acc[m][n][v_] + bv) * scale;
        if (mode == 2) {
          ((float*)out)[(size_t)mrow * EMBED + ncol] = val;
        } else {
          int b = mrow >> 12, s = mrow & (SEQ - 1);
          int h = ncol >> 6, d = ncol & 63;
          size_t idx = (mode == 0) ? ((((size_t)(b * NHEAD + h)) * SEQ + s) * DEPTH + d)
                                   : ((((size_t)(b * NHEAD + h)) * DEPTH + d) * SEQ + s);
          ((bf16*)out)[idx] = (bf16)val;
        }
      }
  }
}

__global__ __launch_bounds__(256, 2) void gemm_qkv(const bf16* __restrict__ Xq, const bf16* __restrict__ Xk,
                                                   const bf16* __restrict__ Xv, const bf16* __restrict__ Tq,
                                                   const bf16* __restrict__ Tk, const bf16* __restrict__ Tv,
                                                   const float* __restrict__ bq, const float* __restrict__ bk,
                                                   const float* __restrict__ bv, bf16* __restrict__ qh,
                                                   bf16* __restrict__ kh, bf16* __restrict__ vT) {
  int z = blockIdx.z;
  const bf16* A = z == 0 ? Xq : (z == 1 ? Xk : Xv);
  const bf16* Bt = z == 0 ? Tq : (z == 1 ? Tk : Tv);
  const float* bias = z == 0 ? bq : (z == 1 ? bk : bv);
  void* out = z == 0 ? (void*)qh : (z == 1 ? (void*)kh : (void*)vT);
  float scale = z == 0 ? QSCALE : 1.0f;
  int mode = z == 2 ? 1 : 0;
  gemm128_body(A, Bt, bias, out, scale, mode);
}

__global__ __launch_bounds__(256, 2) void gemm_o(const bf16* __restrict__ A, const bf16* __restrict__ Bt,
                                                 const float* __restrict__ bias, float* __restrict__ out) {
  gemm128_body(A, Bt, bias, out, 1.0f, 2);
}

// ---------------- flash attention: R4 skeleton + compile-time BUF addressing ----------
// 256 blocks x 512 thr (8 waves): qs = w&3 (64 q-rows), half = w>>2 (2048 keys).
// LDS bytes: K(buf,hh) = buf*32768 + hh*8192 (64 rows x 128B, XOR-swz);
//            V(buf,hh) = buf*32768 + 16384 + hh*8192. Total 64KB + Sm/Sl.
template <int BUF>
__device__ __forceinline__ void tile_step(const char* rbh, const int (&va)[4],
                                          const bf16* kg0, const bf16* vg0, char* kvb,
                                          const float* maskb, int kv, bool stage_next,
                                          const bf16x8 (&qf)[2][4], f32x16 (&oacc)[2][2],
                                          float (&mrun)[2], float (&lrun)[2], int hi) {
  if (stage_next) {
    int nkv = kv + 64;
    gload16(kg0 + (size_t)nkv * DEPTH, kvb + (BUF ^ 1) * 32768);
    gload16(kg0 + (size_t)(nkv + KVH) * DEPTH, kvb + (BUF ^ 1) * 32768 + 8192);
    gload16(vg0 + nkv, kvb + (BUF ^ 1) * 32768 + 16384);
    gload16(vg0 + (nkv + KVH), kvb + (BUF ^ 1) * 32768 + 24576);
  }
  // mask prescale -> MFMA C-operand init (saves zero-init + post-fma)
  f32x16 minit[2];
#pragma unroll
  for (int m2 = 0; m2 < 2; m2++)
#pragma unroll
    for (int g = 0; g < 4; g++) {
      f32x4 f = *(const f32x4*)(maskb + kv + m2 * 32 + g * 8 + 4 * hi);
#pragma unroll
      for (int i = 0; i < 4; i++) minit[m2][4 * g + i] = f[i] * MASKC;
    }
  // K frags (shared by both q2); compile-time imm offsets off 4 vaddrs
  bf16x8 kf[2][4];
#pragma unroll
  for (int m2 = 0; m2 < 2; m2++)
#pragma unroll
    for (int s = 0; s < 4; s++)
      kf[m2][s] = *(const bf16x8*)(rbh + BUF * 32768 + m2 * 4096 + va[s]);

  bf16x8 pa[2][4];
#pragma unroll
  for (int q2 = 0; q2 < 2; q2++) {
    f32x16 s0 = minit[0], s1 = minit[1];
    __builtin_amdgcn_s_setprio(1);
#pragma unroll
    for (int s = 0; s < 4; s++) {
      s0 = __builtin_amdgcn_mfma_f32_32x32x16_bf16(kf[0][s], qf[q2][s], s0, 0, 0, 0);
      s1 = __builtin_amdgcn_mfma_f32_32x32x16_bf16(kf[1][s], qf[q2][s], s1, 0, 0, 0);
    }
    __builtin_amdgcn_s_setprio(0);

    // row max: v_max3 tree + cross-half permlane
    float mx[16];
#pragma unroll
    for (int i = 0; i < 16; i++) mx[i] = fmaxf(s0[i], s1[i]);
    float u0 = max3f(mx[0], mx[1], mx[2]);
    float u1 = max3f(mx[3], mx[4], mx[5]);
    float u2 = max3f(mx[6], mx[7], mx[8]);
    float u3 = max3f(mx[9], mx[10], mx[11]);
    float u4 = max3f(mx[12], mx[13], mx[14]);
    float pmax = fmaxf(max3f(u0, u1, u2), max3f(u3, u4, mx[15]));
    pmax = cross_max(pmax);

    // defer-max (T13)
    if (__any(pmax > mrun[q2] + DEFER_THR)) {
      float mnew = fmaxf(mrun[q2], pmax);
      float alpha = exp2f(mrun[q2] - mnew);
      lrun[q2] *= alpha;
      mrun[q2] = mnew;
#pragma unroll
      for (int r = 0; r < 16; r++) {
        float af = __shfl(alpha, (r & 3) + 8 * (r >> 2) + 4 * hi);
        oacc[q2][0][r] *= af;
        oacc[q2][1][r] *= af;
      }
    }

    // P = exp2(S - m), row sum
    float p[32];
    float rsv[4] = {0.f, 0.f, 0.f, 0.f};
#pragma unroll
    for (int i = 0; i < 16; i++) {
      p[i] = __builtin_amdgcn_exp2f(s0[i] - mrun[q2]);
      rsv[i & 3] += p[i];
    }
#pragma unroll
    for (int i = 0; i < 16; i++) {
      p[16 + i] = __builtin_amdgcn_exp2f(s1[i] - mrun[q2]);
      rsv[i & 3] += p[16 + i];
    }
    lrun[q2] += cross_sum((rsv[0] + rsv[1]) + (rsv[2] + rsv[3]));

    // P -> A-frags (T12)
#pragma unroll
    for (int m2 = 0; m2 < 2; m2++) {
      uint32_t c0 = cvtpk(p[m2 * 16 + 0], p[m2 * 16 + 1]);
      uint32_t c1 = cvtpk(p[m2 * 16 + 2], p[m2 * 16 + 3]);
      uint32_t d0 = cvtpk(p[m2 * 16 + 4], p[m2 * 16 + 5]);
      uint32_t d1 = cvtpk(p[m2 * 16 + 6], p[m2 * 16 + 7]);
      plswap(c0, d0);
      plswap(c1, d1);
      U4 e; e.u[0] = c0; e.u[1] = c1; e.u[2] = d0; e.u[3] = d1;
      pa[q2][m2 * 2 + 0] = e.v;
      uint32_t c2 = cvtpk(p[m2 * 16 + 8], p[m2 * 16 + 9]);
      uint32_t c3 = cvtpk(p[m2 * 16 + 10], p[m2 * 16 + 11]);
      uint32_t d2 = cvtpk(p[m2 * 16 + 12], p[m2 * 16 + 13]);
      uint32_t d3 = cvtpk(p[m2 * 16 + 14], p[m2 * 16 + 15]);
      plswap(c2, d2);
      plswap(c3, d3);
      U4 o; o.u[0] = c2; o.u[1] = c3; o.u[2] = d2; o.u[3] = d3;
      pa[q2][m2 * 2 + 1] = o.v;
    }
  }

  // O += P V
  __builtin_amdgcn_s_setprio(1);
#pragma unroll
  for (int nb = 0; nb < 2; nb++)
#pragma unroll
    for (int ks = 0; ks < 4; ks++) {
      bf16x8 vf = *(const bf16x8*)(rbh + BUF * 32768 + 16384 + nb * 4096 + va[ks]);
      oacc[0][nb] = __builtin_amdgcn_mfma_f32_32x32x16_bf16(pa[0][ks], vf, oacc[0][nb], 0, 0, 0);
      oacc[1][nb] = __builtin_amdgcn_mfma_f32_32x32x16_bf16(pa[1][ks], vf, oacc[1][nb], 0, 0, 0);
    }
  __builtin_amdgcn_s_setprio(0);
  __syncthreads();
}

__global__ __launch_bounds__(512, 2) void flash_attn(const bf16* __restrict__ qh,
                                                     const bf16* __restrict__ kh,
                                                     const bf16* __restrict__ vT,
                                                     const float* __restrict__ mask,
                                                     bf16* __restrict__ O) {
  __shared__ __align__(16) unsigned char smem[65536];
  __shared__ float Sm[4][64];
  __shared__ float Sl[4][64];
  int tid = threadIdx.x, lane = tid & 63, w = tid >> 6;
  int l31 = lane & 31, hi = lane >> 5, l7 = lane & 7;
  int qs = w & 3, half = w >> 2;
  // XCD swizzle: 256 blocks; 32-chunk per XCD = 2 full bh (K/V fits 4MB L2)
  int orig = blockIdx.y * 16 + blockIdx.x;
  int wid = (orig & 7) * 32 + (orig >> 3);
  int bh = wid >> 4, qblk = wid & 15;
  int b = bh >> 3, h = bh & 7;
  int q0 = qblk * 256;
  const bf16* Qb = qh + (size_t)bh * SEQ * DEPTH;
  const bf16* Kb = kh + (size_t)bh * SEQ * DEPTH;
  const bf16* Vb = vT + (size_t)bh * DEPTH * SEQ;
  const float* maskb = mask + (size_t)b * SEQ + half * KVH;

  // staging source (pre-swizzled col, rule 21); dest wave-uniform base
  int srow = tid >> 3;
  int scs = (tid & 7) ^ (srow & 7);
  const bf16* kg0 = Kb + (size_t)srow * DEPTH + scs * 8;
  const bf16* vg0 = Vb + (size_t)srow * SEQ + scs * 8;
  char* kvb = (char*)smem + w * 1024;
  const char* rbh = (const char*)smem + half * 8192;

  // loop-invariant read vaddrs
  int va[4];
#pragma unroll
  for (int s = 0; s < 4; s++) va[s] = l31 * 128 + (((s * 2 + hi) ^ l7) * 16);

  // prologue: stage tile 0 into buf 0
  gload16(kg0, kvb);
  gload16(kg0 + (size_t)KVH * DEPTH, kvb + 8192);
  gload16(vg0, kvb + 16384);
  gload16(vg0 + KVH, kvb + 24576);

  // Q fragments (64 q-rows/wave), resident whole kernel
  bf16x8 qf[2][4];
#pragma unroll
  for (int q2 = 0; q2 < 2; q2++) {
    const bf16* qp = Qb + (size_t)(q0 + qs * 64 + q2 * 32 + l31) * DEPTH + hi * 8;
#pragma unroll
    for (int s = 0; s < 4; s++) qf[q2][s] = *(const bf16x8*)(qp + s * 16);
  }

  f32x16 oacc[2][2];
#pragma unroll
  for (int q2 = 0; q2 < 2; q2++)
#pragma unroll
    for (int nb = 0; nb < 2; nb++)
#pragma unroll
      for (int i = 0; i < 16; i++) oacc[q2][nb][i] = 0.f;
  float mrun[2] = {-__builtin_inff(), -__builtin_inff()};
  float lrun[2] = {0.f, 0.f};

  __syncthreads();

#pragma unroll 1
  for (int kv = 0; kv < KVH; kv += 128) {
    tile_step<0>(rbh, va, kg0, vg0, kvb, maskb, kv, true, qf, oacc, mrun, lrun, hi);
    tile_step<1>(rbh, va, kg0, vg0, kvb, maskb, kv + 64, kv + 128 < KVH, qf, oacc, mrun, lrun, hi);
  }

  // ---- epilogue: merge the two KV-halves via LDS, write [B][S][E] bf16 ----
  float* Oex = (float*)smem;  // [qs][64 q][64 d] f32 = 64KB (reuses KV)
  if (half == 1) {
    if (hi == 0) {
#pragma unroll
      for (int q2 = 0; q2 < 2; q2++) {
        Sm[qs][q2 * 32 + l31] = mrun[q2];
        Sl[qs][q2 * 32 + l31] = lrun[q2];
      }
    }
    float* Op = Oex + qs * 4096;
#pragma unroll
    for (int q2 = 0; q2 < 2; q2++)
#pragma unroll
      for (int nb = 0; nb < 2; nb++)
#pragma unroll
        for (int r = 0; r < 16; r++) {
          int cr = (r & 3) + 8 * (r >> 2) + 4 * hi;
          Op[(q2 * 32 + cr) * 64 + nb * 32 + l31] = oacc[q2][nb][r];
        }
  }
  __syncthreads();
  if (half == 0) {
    float s0[2], s1[2];
#pragma unroll
    for (int q2 = 0; q2 < 2; q2++) {
      float m1 = Sm[qs][q2 * 32 + l31];
      float l1 = Sl[qs][q2 * 32 + l31];
      float mm = fmaxf(mrun[q2], m1);
      float e0 = exp2f(mrun[q2] - mm);
      float e1 = exp2f(m1 - mm);
      float inv = 1.0f / (lrun[q2] * e0 + l1 * e1);
      s0[q2] = e0 * inv;
      s1[q2] = e1 * inv;
    }
    float* Op = Oex + qs * 4096;
    bf16* Ob = O + ((size_t)(b * SEQ + q0 + qs * 64)) * EMBED + h * DEPTH + l31;
#pragma unroll
    for (int q2 = 0; q2 < 2; q2++)
#pragma unroll
      for (int nb = 0; nb < 2; nb++)
#pragma unroll
        for (int r = 0; r < 16; r++) {
          int cr = (r & 3) + 8 * (r >> 2) + 4 * hi;
          float a0 = __shfl(s0[q2], cr);
          float a1 = __shfl(s1[q2], cr);
          float o1 = Op[(q2 * 32 + cr) * 64 + nb * 32 + l31];
          Ob[(size_t)(q2 * 32 + cr) * EMBED + nb * 32] = (bf16)(oacc[q2][nb][r] * a0 + o1 * a1);
        }
  }
}

// ---------------- launch ----------------
extern "C" void kernel_launch(void* const* d_in, const int* in_sizes, int n_in,
                              void* d_out, int out_size, void* d_ws, size_t ws_size,
                              hipStream_t stream) {
  (void)in_sizes; (void)n_in; (void)out_size; (void)ws_size;
  const float* q = (const float*)d_in[0];
  const float* k = (const float*)d_in[1];
  const float* v = (const float*)d_in[2];
  const float* mask = (const float*)d_in[3];
  const float* Wq = (const float*)d_in[4];
  const float* bq = (const float*)d_in[5];
  const float* Wk = (const float*)d_in[6];
  const float* bk = (const float*)d_in[7];
  const float* Wv = (const float*)d_in[8];
  const float* bv = (const float*)d_in[9];
  const float* Wo = (const float*)d_in[10];
  const float* bo = (const float*)d_in[11];

  const size_t NX = (size_t)M_TOTAL * EMBED;
  const size_t NW = (size_t)EMBED * EMBED;
  bf16* Xq = (bf16*)d_ws;
  bf16* Xk = Xq + NX;
  bf16* Xv = Xk + NX;
  bf16* WTq = Xv + NX;
  bf16* WTk = WTq + NW;
  bf16* WTv = WTk + NW;
  bf16* WTo = WTv + NW;
  bf16* qh = WTo + NW;
  bf16* kh = qh + NX;
  bf16* vT = kh + NX;
  bf16* Ow = vT + NX;

  prep<<<dim3(NX / 2048, 4), 256, 0, stream>>>(q, k, v, Xq, Xk, Xv, Wq, Wk, Wv, Wo,
                                               WTq, WTk, WTv, WTo);

  gemm_qkv<<<dim3(EMBED / 128, M_TOTAL / 128, 3), 256, 0, stream>>>(
      Xq, Xk, Xv, WTq, WTk, WTv, bq, bk, bv, qh, kh, vT);

  flash_attn<<<dim3(16, 16), 512, 0, stream>>>(qh, kh, vT, mask, Ow);

  gemm_o<<<dim3(EMBED / 128, M_TOTAL / 128), 256, 0, stream>>>(Ow, WTo, bo, (float*)d_out);
}